// Round 7
// baseline (411.977 us; speedup 1.0000x reference)
//
#include <hip/hip_runtime.h>
#include <hip/hip_bf16.h>

typedef __attribute__((ext_vector_type(4))) float f32x4;
typedef __attribute__((ext_vector_type(8))) short s16x8;
typedef __attribute__((ext_vector_type(4))) short s16x4;

// B=2048 windows, N=64 tokens, C=256, H=32 heads, d=8
#define NWIN 2048

__device__ __forceinline__ ushort f2bf(float f) {
    union { __hip_bfloat16 h; ushort u; } v;
    v.h = __float2bfloat16(f);            // HW cvt, RNE
    return v.u;
}
__device__ __forceinline__ unsigned pk2(float a, float b) {
    union { __hip_bfloat162 h; unsigned u; } v;
    v.h = __float22bfloat162_rn(make_float2(a, b));   // v_cvt_pk_bf16_f32
    return v.u;
}
__device__ __forceinline__ float bf2f(ushort u) {
    union { unsigned u; float f; } v; v.u = ((unsigned)u) << 16;
    return v.f;
}
__device__ __forceinline__ float exp2_hw(float x) {
    float r;
    asm("v_exp_f32 %0, %1" : "=v"(r) : "v"(x));   // v_exp_f32 IS exp2
    return r;
}
union BF4 { unsigned u[2]; unsigned long long ull; s16x4 v; };

#define LOG2E 1.4426950408889634f

// ---- prep: weights -> bf16; bias gather -> f32[h][q][k], pre-scaled by log2e ----
__global__ void prep_kernel(const float* __restrict__ wqkv,
                            const float* __restrict__ wproj,
                            const float* __restrict__ btab,
                            ushort* __restrict__ wq,
                            ushort* __restrict__ wp,
                            float* __restrict__ bf) {
    int t = blockIdx.x * 256 + threadIdx.x;
    if (t < 196608) {                 // 768*256 w_qkv
        wq[t] = f2bf(wqkv[t]);
    } else if (t < 262144) {          // + 256*256 w_proj
        int i = t - 196608;
        wp[i] = f2bf(wproj[i]);
    } else if (t < 393216) {          // + 32*64*64 bias (f32, *log2e)
        int i = t - 262144;
        int h  = i >> 12;
        int rem = i & 4095;
        int qi = rem >> 6;
        int kj = rem & 63;
        int rh = (qi >> 3) - (kj >> 3) + 7;
        int rw = (qi & 7)  - (kj & 7)  + 7;
        bf[i] = btab[(rh * 15 + rw) * 32 + h] * LOG2E;
    }
}

// Fused kernel. Wave w owns heads 4w..4w+3. q/k computed transposed
// (W·x^T) so the GEMM accumulator layout IS the attention fragment layout.
// Pass order K -> Q -> V; each pass runs as two nt-halves with ac[2][2]
// (16 acc) + af[2] (16) to keep the UNIFIED (arch+acc) peak <= ~120 so a
// 512-thread block can double up (4 waves/SIMD -> 2 blocks/CU).
__global__ __launch_bounds__(512) void attn_kernel(
    const float* __restrict__ x,
    const float* __restrict__ bqkv,
    const float* __restrict__ bproj,
    const ushort* __restrict__ wq,
    const ushort* __restrict__ wp,
    const float* __restrict__ biasf,
    float* __restrict__ out)
{
    __shared__ ushort sX[64 * 256];   // 32 KB: x bf16 (swizzled), later out_attn
    __shared__ float  sN[1024];       // 4 KB: [0,512) sum q^2 [tok][d]; [512,) k

    const int tid  = threadIdx.x;
    const int lane = tid & 63;
    const int w    = tid >> 6;
    const int g    = lane >> 4;
    const int c    = lane & 15;
    const int b    = blockIdx.x;

    const f32x4 fz = {0.f, 0.f, 0.f, 0.f};
    const s16x4 z4 = {0, 0, 0, 0};

    sN[tid] = 0.f; sN[tid + 512] = 0.f;

    // ---------- stage x -> bf16 LDS (row-XOR swizzled) ----------
    {
        const float4* xg = (const float4*)(x + (size_t)b * 16384);
        #pragma unroll
        for (int it = 0; it < 8; ++it) {
            int i = tid + it * 512;
            float4 v = xg[i];
            int row = i >> 6;
            int col = (i & 63) << 2;
            int bo = (row * 512 + col * 2) ^ ((row & 7) << 4);
            uint2 u;
            u.x = pk2(v.x, v.y);
            u.y = pk2(v.z, v.w);
            *(uint2*)((char*)sX + bo) = u;
        }
    }
    __syncthreads();

    s16x4 kpk[2][4];   // [hd-tile mt][token-tile nt]; token=16nt+c, hd=4g+e
    s16x4 qpk[2][4];
    s16x4 vpk[4][2];   // token=16kv+4g+j, col=32w+16nj+c

    // ---------- K-pass: transposed GEMM D = Wk · x^T (two nt-halves) ----------
    #pragma unroll
    for (int half = 0; half < 2; ++half) {
        f32x4 ac[2][2];
        ac[0][0] = fz; ac[0][1] = fz; ac[1][0] = fz; ac[1][1] = fz;
        #pragma unroll
        for (int ks = 0; ks < 8; ++ks) {
            s16x8 af[2];
            #pragma unroll
            for (int n2 = 0; n2 < 2; ++n2) {
                int row = 16 * (2 * half + n2) + c;
                int bo = (row * 512 + ks * 64 + g * 16) ^ ((row & 7) << 4);
                af[n2] = *(const s16x8*)((const char*)sX + bo);
            }
            s16x8 wk[2];
            #pragma unroll
            for (int mt = 0; mt < 2; ++mt)
                wk[mt] = *(const s16x8*)(wq + (256 + 32 * w + 16 * mt + c) * 256 + ks * 32 + g * 8);
            #pragma unroll
            for (int mt = 0; mt < 2; ++mt)
                #pragma unroll
                for (int n2 = 0; n2 < 2; ++n2)
                    ac[mt][n2] = __builtin_amdgcn_mfma_f32_16x16x32_bf16(wk[mt], af[n2], ac[mt][n2], 0, 0, 0);
        }
        f32x4 bk0 = *(const f32x4*)(bqkv + 256 + 32 * w + 4 * g);
        f32x4 bk1 = *(const f32x4*)(bqkv + 256 + 32 * w + 16 + 4 * g);
        #pragma unroll
        for (int n2 = 0; n2 < 2; ++n2) {
            int nt = 2 * half + n2;
            ac[0][n2] += bk0; ac[1][n2] += bk1;
            #pragma unroll
            for (int j = 0; j < 4; ++j) {
                float p = ac[0][n2][j] * ac[0][n2][j] + ac[1][n2][j] * ac[1][n2][j];
                p += __shfl_xor(p, 32);
                if (g < 2) atomicAdd(&sN[(16 * nt + c) * 8 + 4 * g + j + 512], p);
            }
            #pragma unroll
            for (int mt = 0; mt < 2; ++mt) {
                BF4 t;
                t.u[0] = pk2(ac[mt][n2][0], ac[mt][n2][1]);
                t.u[1] = pk2(ac[mt][n2][2], ac[mt][n2][3]);
                kpk[mt][nt] = t.v;
            }
        }
    }

    // ---------- Q-pass: same, cols 0..256 (two nt-halves) ----------
    #pragma unroll
    for (int half = 0; half < 2; ++half) {
        f32x4 ac[2][2];
        ac[0][0] = fz; ac[0][1] = fz; ac[1][0] = fz; ac[1][1] = fz;
        #pragma unroll
        for (int ks = 0; ks < 8; ++ks) {
            s16x8 af[2];
            #pragma unroll
            for (int n2 = 0; n2 < 2; ++n2) {
                int row = 16 * (2 * half + n2) + c;
                int bo = (row * 512 + ks * 64 + g * 16) ^ ((row & 7) << 4);
                af[n2] = *(const s16x8*)((const char*)sX + bo);
            }
            s16x8 wqa[2];
            #pragma unroll
            for (int mt = 0; mt < 2; ++mt)
                wqa[mt] = *(const s16x8*)(wq + (32 * w + 16 * mt + c) * 256 + ks * 32 + g * 8);
            #pragma unroll
            for (int mt = 0; mt < 2; ++mt)
                #pragma unroll
                for (int n2 = 0; n2 < 2; ++n2)
                    ac[mt][n2] = __builtin_amdgcn_mfma_f32_16x16x32_bf16(wqa[mt], af[n2], ac[mt][n2], 0, 0, 0);
        }
        f32x4 bq0 = *(const f32x4*)(bqkv + 32 * w + 4 * g);
        f32x4 bq1 = *(const f32x4*)(bqkv + 32 * w + 16 + 4 * g);
        #pragma unroll
        for (int n2 = 0; n2 < 2; ++n2) {
            int nt = 2 * half + n2;
            ac[0][n2] += bq0; ac[1][n2] += bq1;
            #pragma unroll
            for (int j = 0; j < 4; ++j) {
                float p = ac[0][n2][j] * ac[0][n2][j] + ac[1][n2][j] * ac[1][n2][j];
                p += __shfl_xor(p, 32);
                if (g < 2) atomicAdd(&sN[(16 * nt + c) * 8 + 4 * g + j], p);
            }
            #pragma unroll
            for (int mt = 0; mt < 2; ++mt) {
                BF4 t;
                t.u[0] = pk2(ac[mt][n2][0], ac[mt][n2][1]);
                t.u[1] = pk2(ac[mt][n2][2], ac[mt][n2][3]);
                qpk[mt][nt] = t.v;
            }
        }
    }

    // ---------- V-pass: orig orientation, cols 512+32w..+32 (two mi-halves) ----------
    #pragma unroll
    for (int half = 0; half < 2; ++half) {
        f32x4 ac[2][2];   // [mi2][nj]
        ac[0][0] = fz; ac[0][1] = fz; ac[1][0] = fz; ac[1][1] = fz;
        #pragma unroll
        for (int ks = 0; ks < 8; ++ks) {
            s16x8 af[2];
            #pragma unroll
            for (int m2 = 0; m2 < 2; ++m2) {
                int row = 16 * (2 * half + m2) + c;
                int bo = (row * 512 + ks * 64 + g * 16) ^ ((row & 7) << 4);
                af[m2] = *(const s16x8*)((const char*)sX + bo);
            }
            s16x8 wv[2];
            #pragma unroll
            for (int nj = 0; nj < 2; ++nj)
                wv[nj] = *(const s16x8*)(wq + (512 + 32 * w + 16 * nj + c) * 256 + ks * 32 + g * 8);
            #pragma unroll
            for (int m2 = 0; m2 < 2; ++m2)
                #pragma unroll
                for (int nj = 0; nj < 2; ++nj)
                    ac[m2][nj] = __builtin_amdgcn_mfma_f32_16x16x32_bf16(af[m2], wv[nj], ac[m2][nj], 0, 0, 0);
        }
        #pragma unroll
        for (int nj = 0; nj < 2; ++nj) {
            float bv = bqkv[512 + 32 * w + 16 * nj + c];
            #pragma unroll
            for (int m2 = 0; m2 < 2; ++m2) {
                BF4 t;
                t.u[0] = pk2(ac[m2][nj][0] + bv, ac[m2][nj][1] + bv);
                t.u[1] = pk2(ac[m2][nj][2] + bv, ac[m2][nj][3] + bv);
                vpk[2 * half + m2][nj] = t.v;
            }
        }
    }
    __syncthreads();   // norm sums complete; all sX (x) reads complete

    // ---------- normalize packed q/k in place (q gets *log2e for exp2) ----------
    #pragma unroll
    for (int nt = 0; nt < 4; ++nt) {
        // lanes g=0,2 need d 0..3; g=1,3 need d 4..7 -> one b128 each
        f32x4 sq = *(const f32x4*)&sN[(16 * nt + c) * 8 + (g & 1) * 4];
        f32x4 sk = *(const f32x4*)&sN[512 + (16 * nt + c) * 8 + (g & 1) * 4];
        float iq[4], ik[4];
        #pragma unroll
        for (int j = 0; j < 4; ++j) {
            iq[j] = LOG2E * __builtin_amdgcn_rcpf(fmaxf(__builtin_amdgcn_sqrtf(sq[j]), 1e-12f));
            ik[j] = __builtin_amdgcn_rcpf(fmaxf(__builtin_amdgcn_sqrtf(sk[j]), 1e-12f));
        }
        #pragma unroll
        for (int mt = 0; mt < 2; ++mt) {
            BF4 t; t.v = qpk[mt][nt];
            t.u[0] = pk2(bf2f((ushort)(t.u[0] & 0xffff)) * iq[0],
                         bf2f((ushort)(t.u[0] >> 16))    * iq[1]);
            t.u[1] = pk2(bf2f((ushort)(t.u[1] & 0xffff)) * iq[2],
                         bf2f((ushort)(t.u[1] >> 16))    * iq[3]);
            qpk[mt][nt] = t.v;
            t.v = kpk[mt][nt];
            t.u[0] = pk2(bf2f((ushort)(t.u[0] & 0xffff)) * ik[0],
                         bf2f((ushort)(t.u[0] >> 16))    * ik[1]);
            t.u[1] = pk2(bf2f((ushort)(t.u[1] & 0xffff)) * ik[2],
                         bf2f((ushort)(t.u[1] >> 16))    * ik[3]);
            kpk[mt][nt] = t.v;
        }
    }

    // ---------- attention: 4 heads per wave; S one q-tile at a time ----------
    #pragma unroll
    for (int hi = 0; hi < 4; ++hi) {
        const int mt = hi >> 1, par = hi & 1, h = 4 * w + hi;
        const bool keepq = par ? (g >= 2) : (g < 2);
        // V fragment: d=c (c<8), k-token=4g+j; odd heads live at c>=8 -> xor 8
        s16x4 vf[4];
        #pragma unroll
        for (int kv = 0; kv < 4; ++kv) {
            BF4 t; t.v = vpk[kv][mt];
            if (par) {
                t.u[0] = (unsigned)__shfl_xor((int)t.u[0], 8);
                t.u[1] = (unsigned)__shfl_xor((int)t.u[1], 8);
            }
            vf[kv] = (c < 8) ? t.v : z4;
        }
        const float* bhf = biasf + h * 4096;
        #pragma unroll
        for (int tq = 0; tq < 4; ++tq) {
            s16x4 qf = keepq ? qpk[mt][tq] : z4;
            f32x4 S[4];
            #pragma unroll
            for (int tk = 0; tk < 4; ++tk)
                S[tk] = __builtin_amdgcn_mfma_f32_16x16x16bf16_1k(kpk[mt][tk], qf, fz, 0, 0, 0);
            float sum = 0.f;
            #pragma unroll
            for (int tk = 0; tk < 4; ++tk) {
                f32x4 bv4 = *(const f32x4*)(bhf + (16 * tq + c) * 64 + 16 * tk + 4 * g);
                S[tk][0] = exp2_hw(S[tk][0] + bv4[0]);
                S[tk][1] = exp2_hw(S[tk][1] + bv4[1]);
                S[tk][2] = exp2_hw(S[tk][2] + bv4[2]);
                S[tk][3] = exp2_hw(S[tk][3] + bv4[3]);
                sum += S[tk][0] + S[tk][1] + S[tk][2] + S[tk][3];
            }
            sum += __shfl_xor(sum, 16);
            sum += __shfl_xor(sum, 32);
            float rinv = __builtin_amdgcn_rcpf(sum);
            f32x4 o = fz;
            #pragma unroll
            for (int kv = 0; kv < 4; ++kv) {
                BF4 pa;
                pa.u[0] = pk2(S[kv][0], S[kv][1]);
                pa.u[1] = pk2(S[kv][2], S[kv][3]);
                o = __builtin_amdgcn_mfma_f32_16x16x16bf16_1k(pa.v, vf[kv], o, 0, 0, 0);
            }
            if (c < 8) {
                #pragma unroll
                for (int j = 0; j < 4; ++j) {
                    int tok = 16 * tq + 4 * g + j;
                    int bo = (tok * 512 + (h * 8 + c) * 2) ^ ((tok & 7) << 4);
                    *(ushort*)((char*)sX + bo) = f2bf(o[j] * rinv);
                }
            }
        }
    }
    __syncthreads();

    // ---------- proj GEMM (M=64, N=256, K=256) + bias (two mi-halves) ----------
    {
        float* og = out + (size_t)b * 16384;
        #pragma unroll
        for (int half = 0; half < 2; ++half) {
            f32x4 pacc[2][2];
            pacc[0][0] = fz; pacc[0][1] = fz; pacc[1][0] = fz; pacc[1][1] = fz;
            #pragma unroll
            for (int ks = 0; ks < 8; ++ks) {
                s16x8 af[2];
                #pragma unroll
                for (int m2 = 0; m2 < 2; ++m2) {
                    int row = 16 * (2 * half + m2) + c;
                    int bo = (row * 512 + ks * 64 + g * 16) ^ ((row & 7) << 4);
                    af[m2] = *(const s16x8*)((const char*)sX + bo);
                }
                s16x8 wfr[2];
                #pragma unroll
                for (int nj = 0; nj < 2; ++nj)
                    wfr[nj] = *(const s16x8*)(wp + (32 * w + 16 * nj + c) * 256 + ks * 32 + g * 8);
                #pragma unroll
                for (int m2 = 0; m2 < 2; ++m2)
                    #pragma unroll
                    for (int nj = 0; nj < 2; ++nj)
                        pacc[m2][nj] = __builtin_amdgcn_mfma_f32_16x16x32_bf16(af[m2], wfr[nj], pacc[m2][nj], 0, 0, 0);
            }
            #pragma unroll
            for (int nj = 0; nj < 2; ++nj) {
                int col = 32 * w + 16 * nj + c;
                float bp = bproj[col];
                #pragma unroll
                for (int m2 = 0; m2 < 2; ++m2)
                    #pragma unroll
                    for (int j = 0; j < 4; ++j)
                        og[(16 * (2 * half + m2) + 4 * g + j) * 256 + col] = pacc[m2][nj][j] + bp;
            }
        }
    }
}

extern "C" void kernel_launch(void* const* d_in, const int* in_sizes, int n_in,
                              void* d_out, int out_size, void* d_ws, size_t ws_size,
                              hipStream_t stream) {
    const float* x     = (const float*)d_in[0];
    const float* wqkv  = (const float*)d_in[1];
    const float* bqkv  = (const float*)d_in[2];
    const float* wproj = (const float*)d_in[3];
    const float* bproj = (const float*)d_in[4];
    const float* btab  = (const float*)d_in[5];

    ushort* wq_b   = (ushort*)d_ws;                     // 768*256 bf16 = 384 KB
    ushort* wp_b   = wq_b + 196608;                     // 256*256 bf16 = 128 KB
    float*  bias_f = (float*)((char*)d_ws + 524288);    // 32*64*64 f32 = 512 KB

    prep_kernel<<<1536, 256, 0, stream>>>(wqkv, wproj, btab, wq_b, wp_b, bias_f);
    attn_kernel<<<NWIN, 512, 0, stream>>>(x, bqkv, bproj, wq_b, wp_b, bias_f,
                                          (float*)d_out);
}